// Round 10
// baseline (1179.342 us; speedup 1.0000x reference)
//
#include <hip/hip_runtime.h>
#include <cstdint>
#include <cstddef>

// GCN 2-layer, commuted form:  Agg(z) @ W == Agg(z @ W)  (Agg mixes rows, W mixes cols)
//   s1 = bf16(dinv ⊙ x)
//   h' = dinv ⊙ relu( [dinv ⊙ (s1_i + Σ_nbr s1_r)] @ W1 + b1 )   (bf16, pre-scaled for L2)
//   out =               [dinv ⊙ (h'_i + Σ_nbr h'_r)] @ W2 + b2    (fp32)
//
// R10 = R9 (246us) + degree-bucketed node permutation for the fused gather.
// R9 counters: Occ 22->46% but fused dur 45->43us only; VALUBusy 29% => ~70%
// stall is LOCKSTEP+BARRIER imbalance (Poisson(6.4) degrees; block waits on
// max over 64 nodes ~2-3 batches vs avg 1.2). Fix: counting-sort nodes by
// ceil(deg/8) bucket (heavy buckets first) -> homogeneous 64-node tiles.
//  - scan1: + per-block LDS histogram of buckets -> global hist[64]
//  - histscan (1x64): exclusive offsets, DESCENDING bucket order
//  - perm_kernel: slot = atomicAdd(cursor[bucket]); perm[slot] = node
//  - fused: node = perm[slot]; node_s[] in LDS; epilogue scatters to true
//    node rows (256/512B contiguous each). Per-node sum order unchanged.

typedef unsigned int u32;
typedef unsigned short u16;
typedef __attribute__((ext_vector_type(8))) short short8;   // 8 bf16 (4 VGPRs)
typedef __attribute__((ext_vector_type(4))) float f32x4;    // MFMA acc / native vec

__device__ __forceinline__ float bf2f(u32 lo16) {
  union { u32 u; float f; } c; c.u = lo16 << 16; return c.f;
}
__device__ __forceinline__ u32 f2bf(float f) {  // round-to-nearest-even
  union { float f; u32 u; } c; c.f = f;
  return (c.u + 0x7fffu + ((c.u >> 16) & 1u)) >> 16;
}

// W1,W2 [k][n] f32 -> Wt [n][k] bf16; zero row N of s1 and hp. 128 blocks.
__global__ __launch_bounds__(256) void wt_kernel(
    const float* __restrict__ W1, const float* __restrict__ W2,
    u16* __restrict__ Wt1, u16* __restrict__ Wt2,
    u16* __restrict__ s1, u16* __restrict__ hp, int N) {
  int gt = blockIdx.x * 256 + threadIdx.x;  // 0..32767
  const float* W = (gt < 16384) ? W1 : W2;
  u16* Wt = (gt < 16384) ? Wt1 : Wt2;
  int idx = gt & 16383;
  Wt[(idx & 127) * 128 + (idx >> 7)] = (u16)f2bf(W[idx]);
  if (gt < 16) {
    ((uint4*)(s1 + (size_t)N * 128))[gt] = make_uint4(0, 0, 0, 0);
    ((uint4*)(hp + (size_t)N * 128))[gt] = make_uint4(0, 0, 0, 0);
  }
}

__global__ __launch_bounds__(256) void count_kernel(
    const int* __restrict__ cols, const int* __restrict__ rows,
    int* __restrict__ cnt, int E, int N) {
  int e = blockIdx.x * 256 + threadIdx.x;
  if (e >= E) return;
  int c = cols[e];
  int r = rows[e];
  if ((unsigned)c >= (unsigned)N || (unsigned)r >= (unsigned)N) return;
  atomicAdd(&cnt[c], 1);
}

// exclusive scan of cnt[N] -> rowptr[N] (chunk-local); emits dinv; and
// accumulates the global bucket histogram (bucket = min(ceil(deg/8), 63)).
__global__ __launch_bounds__(256) void scan1_kernel(
    const int* __restrict__ cnt, int* __restrict__ rowptr,
    int* __restrict__ bsum, float* __restrict__ dinv,
    int* __restrict__ hist, int N) {
  __shared__ int sd[256];
  __shared__ int lh[64];
  int t = threadIdx.x;
  if (t < 64) lh[t] = 0;
  int base = blockIdx.x * 1024 + t * 4;
  int c0 = (base + 0 < N) ? cnt[base + 0] : 0;
  int c1 = (base + 1 < N) ? cnt[base + 1] : 0;
  int c2 = (base + 2 < N) ? cnt[base + 2] : 0;
  int c3 = (base + 3 < N) ? cnt[base + 3] : 0;
  if (base + 0 < N) dinv[base + 0] = rsqrtf((float)c0 + 1.0f);
  if (base + 1 < N) dinv[base + 1] = rsqrtf((float)c1 + 1.0f);
  if (base + 2 < N) dinv[base + 2] = rsqrtf((float)c2 + 1.0f);
  if (base + 3 < N) dinv[base + 3] = rsqrtf((float)c3 + 1.0f);
  int s = c0 + c1 + c2 + c3;
  sd[t] = s;
  __syncthreads();  // also covers lh init
  for (int off = 1; off < 256; off <<= 1) {
    int v = (t >= off) ? sd[t - off] : 0;
    __syncthreads();
    sd[t] += v;
    __syncthreads();
  }
  int excl = sd[t] - s;
  if (base + 0 < N) rowptr[base + 0] = excl;
  if (base + 1 < N) rowptr[base + 1] = excl + c0;
  if (base + 2 < N) rowptr[base + 2] = excl + c0 + c1;
  if (base + 3 < N) rowptr[base + 3] = excl + c0 + c1 + c2;
  if (t == 255) bsum[blockIdx.x] = sd[255];
  // bucket histogram (LDS first, one global add per bucket per block)
  if (base + 0 < N) atomicAdd(&lh[min((c0 + 7) >> 3, 63)], 1);
  if (base + 1 < N) atomicAdd(&lh[min((c1 + 7) >> 3, 63)], 1);
  if (base + 2 < N) atomicAdd(&lh[min((c2 + 7) >> 3, 63)], 1);
  if (base + 3 < N) atomicAdd(&lh[min((c3 + 7) >> 3, 63)], 1);
  __syncthreads();
  if (t < 64 && lh[t]) atomicAdd(&hist[t], lh[t]);
}

// exclusive offsets over buckets in DESCENDING bucket order (heavy first)
__global__ __launch_bounds__(64) void histscan_kernel(
    const int* __restrict__ hist, int* __restrict__ cursor) {
  __shared__ int sd[64];
  int t = threadIdx.x;
  int v = hist[63 - t];
  sd[t] = v;
  __syncthreads();
  for (int off = 1; off < 64; off <<= 1) {
    int u = (t >= off) ? sd[t - off] : 0;
    __syncthreads();
    sd[t] += u;
    __syncthreads();
  }
  cursor[63 - t] = sd[t] - v;
}

// perm[slot] = node, slots grouped by bucket (order within bucket arbitrary —
// per-node summation order is unchanged, so results are identical).
__global__ __launch_bounds__(256) void perm_kernel(
    const int* __restrict__ cnt, int* __restrict__ cursor,
    int* __restrict__ perm, int N) {
  int i = blockIdx.x * 256 + threadIdx.x;
  if (i >= N) return;
  int b = min((cnt[i] + 7) >> 3, 63);
  int slot = atomicAdd(&cursor[b], 1);
  perm[slot] = i;
}

// rowptr += chunk offset (bsum re-scan) AND s1 = bf16(dinv ⊙ x). NB <= 256.
__global__ __launch_bounds__(256) void finalize_kernel(
    const float* __restrict__ x, const float* __restrict__ dinv,
    int* __restrict__ rowptr, const int* __restrict__ bsum,
    u16* __restrict__ s1, int N, int NB) {
  int b = blockIdx.x, t = threadIdx.x;
  if (b < NB) {  // uniform branch per block -> barriers legal
    __shared__ int sd[256];
    int v = (t < NB) ? bsum[t] : 0;
    sd[t] = v;
    __syncthreads();
    for (int off = 1; off < 256; off <<= 1) {
      int u = (t >= off) ? sd[t - off] : 0;
      __syncthreads();
      sd[t] += u;
      __syncthreads();
    }
    int add = (b == 0) ? 0 : sd[b - 1];  // exclusive chunk prefix
    int base = b * 1024 + t * 4;
#pragma unroll
    for (int k = 0; k < 4; k++)
      if (base + k < N) rowptr[base + k] += add;
    if (b == 0 && t == 255) rowptr[N] = sd[255];  // total edges kept
  }
  int total = N * 16;  // 16B chunks per node row
  for (int idx = b * 256 + t; idx < total; idx += gridDim.x * 256) {
    int node = idx >> 4, l = idx & 15;
    float di = dinv[node];
    const float* xp = x + (size_t)node * 128 + l * 8;
    float4 v0 = *(const float4*)xp;
    float4 v1 = *(const float4*)(xp + 4);
    uint4 p;
    p.x = f2bf(di * v0.x) | (f2bf(di * v0.y) << 16);
    p.y = f2bf(di * v0.z) | (f2bf(di * v0.w) << 16);
    p.z = f2bf(di * v1.x) | (f2bf(di * v1.y) << 16);
    p.w = f2bf(di * v1.z) | (f2bf(di * v1.w) << 16);
    ((uint4*)s1)[idx] = p;
  }
}

// cnt doubles as the cursor: atomicSub returns old count, pos = old-1 in [0,deg)
__global__ __launch_bounds__(256) void fill_kernel(
    const int* __restrict__ cols, const int* __restrict__ rows,
    const int* __restrict__ rowptr, int* __restrict__ cnt,
    int* __restrict__ adj, int E, int N) {
  int e = blockIdx.x * 256 + threadIdx.x;
  if (e >= E) return;
  int c = cols[e];
  int r = rows[e];
  if ((unsigned)c >= (unsigned)N || (unsigned)r >= (unsigned)N) return;
  int pos = atomicSub(&cnt[c], 1) - 1;
  if (pos >= 0) adj[rowptr[c] + pos] = r;
}

// ---------------------------------------------------------------------------
// Fused aggregate + GEMM over PERMUTED node slots. Block = 512 thr (8 waves),
// 64 slots. LDS ~53 KiB -> 3 blocks/CU -> 24 waves/CU.
// Phase 1 (gather): quarter-wave per slot, 2 passes x 32; node = perm[slot]
//   (tiles are bucket-homogeneous -> no lockstep/barrier tail); fp32
//   accumulate of src[self] + Σ src[nbr] (zero-row N pads dummies); write
//   dinv*g to Gs (bf16); node id -> node_s for the epilogue scatter.
// Phase 2 (MFMA): wave = (mt, nhalf): 16 rows x 64 cols, 4 nt x 4 k-steps of
//   16x16x32 bf16, A from Gs, B from Ws. Layouts (m89/m118-verified):
//   A: lane holds A[m=lane&15][k=quad*8+j];  B: B[k=quad*8+j][n=lane&15]
//   C/D: col=lane&15, row=quad*4+reg
// Epilogue L1: hp[node] = bf16(dinv*relu(acc+b1)) via Gs reuse (256B rows).
// Epilogue L2: out[node] = fp32(acc+b2) via fp32 overlay, nontemporal f32x4
//   (512B rows).
// ---------------------------------------------------------------------------
template <int LAYER>
__global__ __launch_bounds__(512, 6) void fused_ag_kernel(
    const uint4* __restrict__ src, const int* __restrict__ rowptr,
    const int* __restrict__ adj, const float* __restrict__ dinv,
    const float* __restrict__ bias, const uint4* __restrict__ Wt,
    const int* __restrict__ perm, void* __restrict__ out, int N) {
  __shared__ __align__(16) u16 smem[128 * 136 + 64 * 136];  // Ws | Gs
  __shared__ float dv_s[64];
  __shared__ int node_s[64];
  u16 (*Ws)[136] = (u16(*)[136])smem;                 // 34816 B (W, [n][k])
  u16 (*Gs)[136] = (u16(*)[136])(smem + 128 * 136);   // 17408 B (gathered rows)
  const int tid = threadIdx.x;
  const int row0 = blockIdx.x * 64;

  // stage W tile (2048 x 16B, 512 thr x 4)
#pragma unroll
  for (int i = 0; i < 4; i++) {
    int linear = tid + i * 512;
    int n = linear >> 4, kq = linear & 15;
    *(uint4*)&Ws[n][kq * 8] = Wt[linear];
  }

  // ---- gather phase: 2 passes x 32 slots (quarter-wave per slot)
  const int qw = tid >> 4;   // 0..31
  const int l = tid & 15;
  int nodes[2];
#pragma unroll
  for (int p = 0; p < 2; ++p) {
    int slot = row0 + p * 32 + qw;
    nodes[p] = (slot < N) ? perm[slot] : -1;
  }
  int begs[2], ends[2];
#pragma unroll
  for (int p = 0; p < 2; ++p) {
    begs[p] = 0; ends[p] = 0;
    if (nodes[p] >= 0) { begs[p] = rowptr[nodes[p]]; ends[p] = rowptr[nodes[p] + 1]; }
  }
#pragma unroll
  for (int pass = 0; pass < 2; ++pass) {
    int lrow = pass * 32 + qw;
    int node = nodes[pass];
    float a[8] = {0.f, 0.f, 0.f, 0.f, 0.f, 0.f, 0.f, 0.f};
    float di = 0.f;
    if (node >= 0) {
      di = dinv[node];
      uint4 sv = src[(size_t)node * 16 + l];
      a[0] = bf2f(sv.x & 0xffff); a[1] = bf2f(sv.x >> 16);
      a[2] = bf2f(sv.y & 0xffff); a[3] = bf2f(sv.y >> 16);
      a[4] = bf2f(sv.z & 0xffff); a[5] = bf2f(sv.z >> 16);
      a[6] = bf2f(sv.w & 0xffff); a[7] = bf2f(sv.w >> 16);
      int beg = begs[pass], end = ends[pass];
      for (int j = beg; j < end; j += 8) {
        int sidx[8];
#pragma unroll
        for (int k = 0; k < 8; k++) {
          int jj = j + k;
          sidx[k] = (jj < end) ? adj[jj] : N;  // N = zero row
        }
        uint4 v[8];
#pragma unroll
        for (int k = 0; k < 8; k++) v[k] = src[(size_t)sidx[k] * 16 + l];
#pragma unroll
        for (int k = 0; k < 8; k++) {
          a[0] += bf2f(v[k].x & 0xffff); a[1] += bf2f(v[k].x >> 16);
          a[2] += bf2f(v[k].y & 0xffff); a[3] += bf2f(v[k].y >> 16);
          a[4] += bf2f(v[k].z & 0xffff); a[5] += bf2f(v[k].z >> 16);
          a[6] += bf2f(v[k].w & 0xffff); a[7] += bf2f(v[k].w >> 16);
        }
      }
    }
    uint4 p;
    p.x = f2bf(di * a[0]) | (f2bf(di * a[1]) << 16);
    p.y = f2bf(di * a[2]) | (f2bf(di * a[3]) << 16);
    p.z = f2bf(di * a[4]) | (f2bf(di * a[5]) << 16);
    p.w = f2bf(di * a[6]) | (f2bf(di * a[7]) << 16);
    *(uint4*)&Gs[lrow][l * 8] = p;
    if (l == 0) { dv_s[lrow] = di; node_s[lrow] = node; }
  }
  __syncthreads();

  // ---- MFMA phase: wave (mt, nhalf) owns rows mt*16..+15, cols nhalf*64..+63
  const int wave = tid >> 6, lane = tid & 63;
  const int lm = lane & 15, quad = lane >> 4;
  const int m0 = (wave >> 1) * 16;
  const int nh = wave & 1;

  float bv[4];  // hoisted above k-loop: latency hides under MFMA
#pragma unroll
  for (int nt = 0; nt < 4; nt++) bv[nt] = bias[(nh * 4 + nt) * 16 + lm];

  f32x4 acc[4];
#pragma unroll
  for (int nt = 0; nt < 4; nt++) acc[nt] = (f32x4){0.f, 0.f, 0.f, 0.f};
#pragma unroll
  for (int k0 = 0; k0 < 128; k0 += 32) {
    short8 afrag = *(const short8*)&Gs[m0 + lm][k0 + quad * 8];
#pragma unroll
    for (int nt = 0; nt < 4; nt++) {
      short8 bfrag = *(const short8*)&Ws[(nh * 4 + nt) * 16 + lm][k0 + quad * 8];
      acc[nt] = __builtin_amdgcn_mfma_f32_16x16x32_bf16(afrag, bfrag, acc[nt], 0, 0, 0);
    }
  }

  __syncthreads();  // Ws/Gs dead; reuse as epilogue staging
  if (LAYER == 1) {
    int rbase = m0 + quad * 4;
#pragma unroll
    for (int r = 0; r < 4; r++) {
      int lrow = rbase + r;
      float dv = dv_s[lrow];
#pragma unroll
      for (int nt = 0; nt < 4; nt++) {
        float v = fmaxf(acc[nt][r] + bv[nt], 0.f);
        Gs[lrow][(nh * 4 + nt) * 16 + lm] = (u16)f2bf(v * dv);
      }
    }
    __syncthreads();
    u16* C = (u16*)out;
#pragma unroll
    for (int i = 0; i < 2; i++) {
      int linear = tid + i * 512;  // 0..1023 = 64 rows x 16 uint4-chunks
      int row = linear >> 4, c8 = linear & 15;
      int grow = node_s[row];
      if (grow >= 0)
        *(uint4*)(C + (size_t)grow * 128 + c8 * 8) = *(const uint4*)&Gs[row][c8 * 8];
    }
  } else {
    float (*Fs)[132] = (float(*)[132])smem;  // 64*132*4 = 33792 B (Ws region)
    int rbase = m0 + quad * 4;
#pragma unroll
    for (int r = 0; r < 4; r++) {
      int lrow = rbase + r;
#pragma unroll
      for (int nt = 0; nt < 4; nt++)
        Fs[lrow][(nh * 4 + nt) * 16 + lm] = acc[nt][r] + bv[nt];
    }
    __syncthreads();
    float* C = (float*)out;
#pragma unroll
    for (int i = 0; i < 4; i++) {
      int linear = tid + i * 512;  // 0..2047 = 64 rows x 32 f32x4-chunks
      int row = linear >> 5, c4 = linear & 31;
      int grow = node_s[row];
      if (grow >= 0) {
        f32x4 v = *(const f32x4*)&Fs[row][c4 * 4];
        __builtin_nontemporal_store(v, (f32x4*)(C + (size_t)grow * 128 + c4 * 4));
      }
    }
  }
}

extern "C" void kernel_launch(void* const* d_in, const int* in_sizes, int n_in,
                              void* d_out, int out_size, void* d_ws, size_t ws_size,
                              hipStream_t stream) {
  const float* x  = (const float*)d_in[0];
  const int*   ei = (const int*)d_in[1];
  const float* W1 = (const float*)d_in[2];
  const float* b1 = (const float*)d_in[3];
  const float* W2 = (const float*)d_in[4];
  const float* b2 = (const float*)d_in[5];
  float* out = (float*)d_out;

  const int F = 128;
  const int N = in_sizes[0] / F;
  const int E = in_sizes[1] / 2;
  const int* rows = ei;       // edge_index[0] = source
  const int* cols = ei + E;   // edge_index[1] = destination

  // workspace layout (~56 MB)
  u16*   Wt1    = (u16*)d_ws;                          // 128*128 bf16 (W1^T)
  u16*   Wt2    = Wt1 + 128 * 128;                     // 128*128 bf16 (W2^T)
  u16*   s1     = Wt2 + 128 * 128;                     // (N+1)*128 bf16 (dinv⊙x + zero row)
  u16*   hp     = s1 + (size_t)(N + 1) * F;            // (N+1)*128 bf16 (dinv⊙h + zero row)
  float* dinv   = (float*)(hp + (size_t)(N + 1) * F);  // N f32
  int*   cnt    = (int*)(dinv + N);                    // N i32 (count, then cursor)
  int*   hist   = cnt + N;                             // 64 i32 (bucket histogram)
  int*   rowptr = hist + 64;                           // N+1 i32
  int*   adj    = rowptr + (N + 1);                    // E i32
  int*   bsum   = adj + E;                             // 256 i32
  int*   cursor = bsum + 256;                          // 64 i32
  int*   perm   = cursor + 64;                         // N i32

  const int NB = (N + 1023) / 1024;  // <= 256 (N <= 262144)
  int eblocks = (E + 255) / 256;
  int nblocks = (N + 255) / 256;
  int fblocks = (NB > 784) ? NB : 784;

  hipMemsetAsync(cnt, 0, (size_t)(N + 64) * sizeof(int), stream);  // cnt + hist
  wt_kernel<<<128, 256, 0, stream>>>(W1, W2, Wt1, Wt2, s1, hp, N);
  count_kernel<<<eblocks, 256, 0, stream>>>(cols, rows, cnt, E, N);
  scan1_kernel<<<NB, 256, 0, stream>>>(cnt, rowptr, bsum, dinv, hist, N);
  histscan_kernel<<<1, 64, 0, stream>>>(hist, cursor);
  perm_kernel<<<nblocks, 256, 0, stream>>>(cnt, cursor, perm, N);
  finalize_kernel<<<fblocks, 256, 0, stream>>>(x, dinv, rowptr, bsum, s1, N, NB);
  fill_kernel<<<eblocks, 256, 0, stream>>>(cols, rows, rowptr, cnt, adj, E, N);

  int gblocks = (N + 63) / 64;
  // layer 1: hp = dinv ⊙ relu([dinv ⊙ Agg-sum(s1)] @ W1 + b1)  (bf16)
  fused_ag_kernel<1><<<gblocks, 512, 0, stream>>>(
      (const uint4*)s1, rowptr, adj, dinv, b1, (const uint4*)Wt1, perm, hp, N);
  // layer 2: out = [dinv ⊙ Agg-sum(hp)] @ W2 + b2  (fp32)
  fused_ag_kernel<2><<<gblocks, 512, 0, stream>>>(
      (const uint4*)hp, rowptr, adj, dinv, b2, (const uint4*)Wt2, perm, out, N);
}

// Round 11
// 255.818 us; speedup vs baseline: 4.6101x; 4.6101x over previous
//
#include <hip/hip_runtime.h>
#include <cstdint>
#include <cstddef>

// GCN 2-layer, commuted form:  Agg(z) @ W == Agg(z @ W)  (Agg mixes rows, W mixes cols)
//   s1 = bf16(dinv ⊙ x)
//   h' = dinv ⊙ relu( [dinv ⊙ (s1_i + Σ_nbr s1_r)] @ W1 + b1 )   (bf16, pre-scaled for L2)
//   out =               [dinv ⊙ (h'_i + Σ_nbr h'_r)] @ W2 + b2    (fp32)
//
// R11 = R10 with the perm_kernel atomic-contention bug fixed (R10: 924us —
// ~100k global atomicAdd on 2 hot cursor words; Guideline-12 violation).
// Fix: two-level ranking — LDS atomic intra-block rank + ONE global
// atomicAdd per (bucket, block) slab reservation (~1.5k atomics over 64
// addresses). Bucket grouping preserved; within-bucket order arbitrary
// (per-node summation order unchanged -> identical numerics).
// Everything else identical to R10 (degree-bucketed fused gather).

typedef unsigned int u32;
typedef unsigned short u16;
typedef __attribute__((ext_vector_type(8))) short short8;   // 8 bf16 (4 VGPRs)
typedef __attribute__((ext_vector_type(4))) float f32x4;    // MFMA acc / native vec

__device__ __forceinline__ float bf2f(u32 lo16) {
  union { u32 u; float f; } c; c.u = lo16 << 16; return c.f;
}
__device__ __forceinline__ u32 f2bf(float f) {  // round-to-nearest-even
  union { float f; u32 u; } c; c.f = f;
  return (c.u + 0x7fffu + ((c.u >> 16) & 1u)) >> 16;
}

// W1,W2 [k][n] f32 -> Wt [n][k] bf16; zero row N of s1 and hp. 128 blocks.
__global__ __launch_bounds__(256) void wt_kernel(
    const float* __restrict__ W1, const float* __restrict__ W2,
    u16* __restrict__ Wt1, u16* __restrict__ Wt2,
    u16* __restrict__ s1, u16* __restrict__ hp, int N) {
  int gt = blockIdx.x * 256 + threadIdx.x;  // 0..32767
  const float* W = (gt < 16384) ? W1 : W2;
  u16* Wt = (gt < 16384) ? Wt1 : Wt2;
  int idx = gt & 16383;
  Wt[(idx & 127) * 128 + (idx >> 7)] = (u16)f2bf(W[idx]);
  if (gt < 16) {
    ((uint4*)(s1 + (size_t)N * 128))[gt] = make_uint4(0, 0, 0, 0);
    ((uint4*)(hp + (size_t)N * 128))[gt] = make_uint4(0, 0, 0, 0);
  }
}

__global__ __launch_bounds__(256) void count_kernel(
    const int* __restrict__ cols, const int* __restrict__ rows,
    int* __restrict__ cnt, int E, int N) {
  int e = blockIdx.x * 256 + threadIdx.x;
  if (e >= E) return;
  int c = cols[e];
  int r = rows[e];
  if ((unsigned)c >= (unsigned)N || (unsigned)r >= (unsigned)N) return;
  atomicAdd(&cnt[c], 1);
}

// exclusive scan of cnt[N] -> rowptr[N] (chunk-local); emits dinv; and
// accumulates the global bucket histogram (bucket = min(ceil(deg/8), 63)).
__global__ __launch_bounds__(256) void scan1_kernel(
    const int* __restrict__ cnt, int* __restrict__ rowptr,
    int* __restrict__ bsum, float* __restrict__ dinv,
    int* __restrict__ hist, int N) {
  __shared__ int sd[256];
  __shared__ int lh[64];
  int t = threadIdx.x;
  if (t < 64) lh[t] = 0;
  int base = blockIdx.x * 1024 + t * 4;
  int c0 = (base + 0 < N) ? cnt[base + 0] : 0;
  int c1 = (base + 1 < N) ? cnt[base + 1] : 0;
  int c2 = (base + 2 < N) ? cnt[base + 2] : 0;
  int c3 = (base + 3 < N) ? cnt[base + 3] : 0;
  if (base + 0 < N) dinv[base + 0] = rsqrtf((float)c0 + 1.0f);
  if (base + 1 < N) dinv[base + 1] = rsqrtf((float)c1 + 1.0f);
  if (base + 2 < N) dinv[base + 2] = rsqrtf((float)c2 + 1.0f);
  if (base + 3 < N) dinv[base + 3] = rsqrtf((float)c3 + 1.0f);
  int s = c0 + c1 + c2 + c3;
  sd[t] = s;
  __syncthreads();  // also covers lh init
  for (int off = 1; off < 256; off <<= 1) {
    int v = (t >= off) ? sd[t - off] : 0;
    __syncthreads();
    sd[t] += v;
    __syncthreads();
  }
  int excl = sd[t] - s;
  if (base + 0 < N) rowptr[base + 0] = excl;
  if (base + 1 < N) rowptr[base + 1] = excl + c0;
  if (base + 2 < N) rowptr[base + 2] = excl + c0 + c1;
  if (base + 3 < N) rowptr[base + 3] = excl + c0 + c1 + c2;
  if (t == 255) bsum[blockIdx.x] = sd[255];
  // bucket histogram (LDS first, one global add per bucket per block)
  if (base + 0 < N) atomicAdd(&lh[min((c0 + 7) >> 3, 63)], 1);
  if (base + 1 < N) atomicAdd(&lh[min((c1 + 7) >> 3, 63)], 1);
  if (base + 2 < N) atomicAdd(&lh[min((c2 + 7) >> 3, 63)], 1);
  if (base + 3 < N) atomicAdd(&lh[min((c3 + 7) >> 3, 63)], 1);
  __syncthreads();
  if (t < 64 && lh[t]) atomicAdd(&hist[t], lh[t]);
}

// exclusive offsets over buckets in DESCENDING bucket order (heavy first)
__global__ __launch_bounds__(64) void histscan_kernel(
    const int* __restrict__ hist, int* __restrict__ cursor) {
  __shared__ int sd[64];
  int t = threadIdx.x;
  int v = hist[63 - t];
  sd[t] = v;
  __syncthreads();
  for (int off = 1; off < 64; off <<= 1) {
    int u = (t >= off) ? sd[t - off] : 0;
    __syncthreads();
    sd[t] += u;
    __syncthreads();
  }
  cursor[63 - t] = sd[t] - v;
}

// perm[slot] = node, grouped by bucket. Two-level ranking:
//   lrank = LDS atomic within (block, bucket);
//   lbase = ONE global atomicAdd per (block, bucket) slab;
//   slot  = lbase + lrank.  (R10 did one global atomic PER NODE on ~2 hot
//   words -> 924us serialization. This is ~1.5k atomics over 64 words.)
__global__ __launch_bounds__(256) void perm_kernel(
    const int* __restrict__ cnt, int* __restrict__ cursor,
    int* __restrict__ perm, int N) {
  __shared__ int lh[64];
  __shared__ int lbase[64];
  int t = threadIdx.x;
  int i = blockIdx.x * 256 + t;
  if (t < 64) lh[t] = 0;
  __syncthreads();
  int b = 0, lrank = 0;
  if (i < N) {
    b = min((cnt[i] + 7) >> 3, 63);
    lrank = atomicAdd(&lh[b], 1);  // LDS atomic: intra-block rank
  }
  __syncthreads();
  if (t < 64 && lh[t] > 0) lbase[t] = atomicAdd(&cursor[t], lh[t]);
  __syncthreads();
  if (i < N) perm[lbase[b] + lrank] = i;
}

// rowptr += chunk offset (bsum re-scan) AND s1 = bf16(dinv ⊙ x). NB <= 256.
__global__ __launch_bounds__(256) void finalize_kernel(
    const float* __restrict__ x, const float* __restrict__ dinv,
    int* __restrict__ rowptr, const int* __restrict__ bsum,
    u16* __restrict__ s1, int N, int NB) {
  int b = blockIdx.x, t = threadIdx.x;
  if (b < NB) {  // uniform branch per block -> barriers legal
    __shared__ int sd[256];
    int v = (t < NB) ? bsum[t] : 0;
    sd[t] = v;
    __syncthreads();
    for (int off = 1; off < 256; off <<= 1) {
      int u = (t >= off) ? sd[t - off] : 0;
      __syncthreads();
      sd[t] += u;
      __syncthreads();
    }
    int add = (b == 0) ? 0 : sd[b - 1];  // exclusive chunk prefix
    int base = b * 1024 + t * 4;
#pragma unroll
    for (int k = 0; k < 4; k++)
      if (base + k < N) rowptr[base + k] += add;
    if (b == 0 && t == 255) rowptr[N] = sd[255];  // total edges kept
  }
  int total = N * 16;  // 16B chunks per node row
  for (int idx = b * 256 + t; idx < total; idx += gridDim.x * 256) {
    int node = idx >> 4, l = idx & 15;
    float di = dinv[node];
    const float* xp = x + (size_t)node * 128 + l * 8;
    float4 v0 = *(const float4*)xp;
    float4 v1 = *(const float4*)(xp + 4);
    uint4 p;
    p.x = f2bf(di * v0.x) | (f2bf(di * v0.y) << 16);
    p.y = f2bf(di * v0.z) | (f2bf(di * v0.w) << 16);
    p.z = f2bf(di * v1.x) | (f2bf(di * v1.y) << 16);
    p.w = f2bf(di * v1.z) | (f2bf(di * v1.w) << 16);
    ((uint4*)s1)[idx] = p;
  }
}

// cnt doubles as the cursor: atomicSub returns old count, pos = old-1 in [0,deg)
__global__ __launch_bounds__(256) void fill_kernel(
    const int* __restrict__ cols, const int* __restrict__ rows,
    const int* __restrict__ rowptr, int* __restrict__ cnt,
    int* __restrict__ adj, int E, int N) {
  int e = blockIdx.x * 256 + threadIdx.x;
  if (e >= E) return;
  int c = cols[e];
  int r = rows[e];
  if ((unsigned)c >= (unsigned)N || (unsigned)r >= (unsigned)N) return;
  int pos = atomicSub(&cnt[c], 1) - 1;
  if (pos >= 0) adj[rowptr[c] + pos] = r;
}

// ---------------------------------------------------------------------------
// Fused aggregate + GEMM over PERMUTED node slots. Block = 512 thr (8 waves),
// 64 slots. LDS ~53 KiB -> 3 blocks/CU -> 24 waves/CU.
// Phase 1 (gather): quarter-wave per slot, 2 passes x 32; node = perm[slot]
//   (tiles are bucket-homogeneous -> no lockstep/barrier tail); fp32
//   accumulate of src[self] + Σ src[nbr] (zero-row N pads dummies); write
//   dinv*g to Gs (bf16); node id -> node_s for the epilogue scatter.
// Phase 2 (MFMA): wave = (mt, nhalf): 16 rows x 64 cols, 4 nt x 4 k-steps of
//   16x16x32 bf16, A from Gs, B from Ws. Layouts (m89/m118-verified):
//   A: lane holds A[m=lane&15][k=quad*8+j];  B: B[k=quad*8+j][n=lane&15]
//   C/D: col=lane&15, row=quad*4+reg
// Epilogue L1: hp[node] = bf16(dinv*relu(acc+b1)) via Gs reuse (256B rows).
// Epilogue L2: out[node] = fp32(acc+b2) via fp32 overlay, nontemporal f32x4
//   (512B rows).
// ---------------------------------------------------------------------------
template <int LAYER>
__global__ __launch_bounds__(512, 6) void fused_ag_kernel(
    const uint4* __restrict__ src, const int* __restrict__ rowptr,
    const int* __restrict__ adj, const float* __restrict__ dinv,
    const float* __restrict__ bias, const uint4* __restrict__ Wt,
    const int* __restrict__ perm, void* __restrict__ out, int N) {
  __shared__ __align__(16) u16 smem[128 * 136 + 64 * 136];  // Ws | Gs
  __shared__ float dv_s[64];
  __shared__ int node_s[64];
  u16 (*Ws)[136] = (u16(*)[136])smem;                 // 34816 B (W, [n][k])
  u16 (*Gs)[136] = (u16(*)[136])(smem + 128 * 136);   // 17408 B (gathered rows)
  const int tid = threadIdx.x;
  const int row0 = blockIdx.x * 64;

  // stage W tile (2048 x 16B, 512 thr x 4)
#pragma unroll
  for (int i = 0; i < 4; i++) {
    int linear = tid + i * 512;
    int n = linear >> 4, kq = linear & 15;
    *(uint4*)&Ws[n][kq * 8] = Wt[linear];
  }

  // ---- gather phase: 2 passes x 32 slots (quarter-wave per slot)
  const int qw = tid >> 4;   // 0..31
  const int l = tid & 15;
  int nodes[2];
#pragma unroll
  for (int p = 0; p < 2; ++p) {
    int slot = row0 + p * 32 + qw;
    nodes[p] = (slot < N) ? perm[slot] : -1;
  }
  int begs[2], ends[2];
#pragma unroll
  for (int p = 0; p < 2; ++p) {
    begs[p] = 0; ends[p] = 0;
    if (nodes[p] >= 0) { begs[p] = rowptr[nodes[p]]; ends[p] = rowptr[nodes[p] + 1]; }
  }
#pragma unroll
  for (int pass = 0; pass < 2; ++pass) {
    int lrow = pass * 32 + qw;
    int node = nodes[pass];
    float a[8] = {0.f, 0.f, 0.f, 0.f, 0.f, 0.f, 0.f, 0.f};
    float di = 0.f;
    if (node >= 0) {
      di = dinv[node];
      uint4 sv = src[(size_t)node * 16 + l];
      a[0] = bf2f(sv.x & 0xffff); a[1] = bf2f(sv.x >> 16);
      a[2] = bf2f(sv.y & 0xffff); a[3] = bf2f(sv.y >> 16);
      a[4] = bf2f(sv.z & 0xffff); a[5] = bf2f(sv.z >> 16);
      a[6] = bf2f(sv.w & 0xffff); a[7] = bf2f(sv.w >> 16);
      int beg = begs[pass], end = ends[pass];
      for (int j = beg; j < end; j += 8) {
        int sidx[8];
#pragma unroll
        for (int k = 0; k < 8; k++) {
          int jj = j + k;
          sidx[k] = (jj < end) ? adj[jj] : N;  // N = zero row
        }
        uint4 v[8];
#pragma unroll
        for (int k = 0; k < 8; k++) v[k] = src[(size_t)sidx[k] * 16 + l];
#pragma unroll
        for (int k = 0; k < 8; k++) {
          a[0] += bf2f(v[k].x & 0xffff); a[1] += bf2f(v[k].x >> 16);
          a[2] += bf2f(v[k].y & 0xffff); a[3] += bf2f(v[k].y >> 16);
          a[4] += bf2f(v[k].z & 0xffff); a[5] += bf2f(v[k].z >> 16);
          a[6] += bf2f(v[k].w & 0xffff); a[7] += bf2f(v[k].w >> 16);
        }
      }
    }
    uint4 p;
    p.x = f2bf(di * a[0]) | (f2bf(di * a[1]) << 16);
    p.y = f2bf(di * a[2]) | (f2bf(di * a[3]) << 16);
    p.z = f2bf(di * a[4]) | (f2bf(di * a[5]) << 16);
    p.w = f2bf(di * a[6]) | (f2bf(di * a[7]) << 16);
    *(uint4*)&Gs[lrow][l * 8] = p;
    if (l == 0) { dv_s[lrow] = di; node_s[lrow] = node; }
  }
  __syncthreads();

  // ---- MFMA phase: wave (mt, nhalf) owns rows mt*16..+15, cols nhalf*64..+63
  const int wave = tid >> 6, lane = tid & 63;
  const int lm = lane & 15, quad = lane >> 4;
  const int m0 = (wave >> 1) * 16;
  const int nh = wave & 1;

  float bv[4];  // hoisted above k-loop: latency hides under MFMA
#pragma unroll
  for (int nt = 0; nt < 4; nt++) bv[nt] = bias[(nh * 4 + nt) * 16 + lm];

  f32x4 acc[4];
#pragma unroll
  for (int nt = 0; nt < 4; nt++) acc[nt] = (f32x4){0.f, 0.f, 0.f, 0.f};
#pragma unroll
  for (int k0 = 0; k0 < 128; k0 += 32) {
    short8 afrag = *(const short8*)&Gs[m0 + lm][k0 + quad * 8];
#pragma unroll
    for (int nt = 0; nt < 4; nt++) {
      short8 bfrag = *(const short8*)&Ws[(nh * 4 + nt) * 16 + lm][k0 + quad * 8];
      acc[nt] = __builtin_amdgcn_mfma_f32_16x16x32_bf16(afrag, bfrag, acc[nt], 0, 0, 0);
    }
  }

  __syncthreads();  // Ws/Gs dead; reuse as epilogue staging
  if (LAYER == 1) {
    int rbase = m0 + quad * 4;
#pragma unroll
    for (int r = 0; r < 4; r++) {
      int lrow = rbase + r;
      float dv = dv_s[lrow];
#pragma unroll
      for (int nt = 0; nt < 4; nt++) {
        float v = fmaxf(acc[nt][r] + bv[nt], 0.f);
        Gs[lrow][(nh * 4 + nt) * 16 + lm] = (u16)f2bf(v * dv);
      }
    }
    __syncthreads();
    u16* C = (u16*)out;
#pragma unroll
    for (int i = 0; i < 2; i++) {
      int linear = tid + i * 512;  // 0..1023 = 64 rows x 16 uint4-chunks
      int row = linear >> 4, c8 = linear & 15;
      int grow = node_s[row];
      if (grow >= 0)
        *(uint4*)(C + (size_t)grow * 128 + c8 * 8) = *(const uint4*)&Gs[row][c8 * 8];
    }
  } else {
    float (*Fs)[132] = (float(*)[132])smem;  // 64*132*4 = 33792 B (Ws region)
    int rbase = m0 + quad * 4;
#pragma unroll
    for (int r = 0; r < 4; r++) {
      int lrow = rbase + r;
#pragma unroll
      for (int nt = 0; nt < 4; nt++)
        Fs[lrow][(nh * 4 + nt) * 16 + lm] = acc[nt][r] + bv[nt];
    }
    __syncthreads();
    float* C = (float*)out;
#pragma unroll
    for (int i = 0; i < 4; i++) {
      int linear = tid + i * 512;  // 0..2047 = 64 rows x 32 f32x4-chunks
      int row = linear >> 5, c4 = linear & 31;
      int grow = node_s[row];
      if (grow >= 0) {
        f32x4 v = *(const f32x4*)&Fs[row][c4 * 4];
        __builtin_nontemporal_store(v, (f32x4*)(C + (size_t)grow * 128 + c4 * 4));
      }
    }
  }
}

extern "C" void kernel_launch(void* const* d_in, const int* in_sizes, int n_in,
                              void* d_out, int out_size, void* d_ws, size_t ws_size,
                              hipStream_t stream) {
  const float* x  = (const float*)d_in[0];
  const int*   ei = (const int*)d_in[1];
  const float* W1 = (const float*)d_in[2];
  const float* b1 = (const float*)d_in[3];
  const float* W2 = (const float*)d_in[4];
  const float* b2 = (const float*)d_in[5];
  float* out = (float*)d_out;

  const int F = 128;
  const int N = in_sizes[0] / F;
  const int E = in_sizes[1] / 2;
  const int* rows = ei;       // edge_index[0] = source
  const int* cols = ei + E;   // edge_index[1] = destination

  // workspace layout (~56 MB)
  u16*   Wt1    = (u16*)d_ws;                          // 128*128 bf16 (W1^T)
  u16*   Wt2    = Wt1 + 128 * 128;                     // 128*128 bf16 (W2^T)
  u16*   s1     = Wt2 + 128 * 128;                     // (N+1)*128 bf16 (dinv⊙x + zero row)
  u16*   hp     = s1 + (size_t)(N + 1) * F;            // (N+1)*128 bf16 (dinv⊙h + zero row)
  float* dinv   = (float*)(hp + (size_t)(N + 1) * F);  // N f32
  int*   cnt    = (int*)(dinv + N);                    // N i32 (count, then cursor)
  int*   hist   = cnt + N;                             // 64 i32 (bucket histogram)
  int*   rowptr = hist + 64;                           // N+1 i32
  int*   adj    = rowptr + (N + 1);                    // E i32
  int*   bsum   = adj + E;                             // 256 i32
  int*   cursor = bsum + 256;                          // 64 i32
  int*   perm   = cursor + 64;                         // N i32

  const int NB = (N + 1023) / 1024;  // <= 256 (N <= 262144)
  int eblocks = (E + 255) / 256;
  int nblocks = (N + 255) / 256;
  int fblocks = (NB > 784) ? NB : 784;

  hipMemsetAsync(cnt, 0, (size_t)(N + 64) * sizeof(int), stream);  // cnt + hist
  wt_kernel<<<128, 256, 0, stream>>>(W1, W2, Wt1, Wt2, s1, hp, N);
  count_kernel<<<eblocks, 256, 0, stream>>>(cols, rows, cnt, E, N);
  scan1_kernel<<<NB, 256, 0, stream>>>(cnt, rowptr, bsum, dinv, hist, N);
  histscan_kernel<<<1, 64, 0, stream>>>(hist, cursor);
  perm_kernel<<<nblocks, 256, 0, stream>>>(cnt, cursor, perm, N);
  finalize_kernel<<<fblocks, 256, 0, stream>>>(x, dinv, rowptr, bsum, s1, N, NB);
  fill_kernel<<<eblocks, 256, 0, stream>>>(cols, rows, rowptr, cnt, adj, E, N);

  int gblocks = (N + 63) / 64;
  // layer 1: hp = dinv ⊙ relu([dinv ⊙ Agg-sum(s1)] @ W1 + b1)  (bf16)
  fused_ag_kernel<1><<<gblocks, 512, 0, stream>>>(
      (const uint4*)s1, rowptr, adj, dinv, b1, (const uint4*)Wt1, perm, hp, N);
  // layer 2: out = [dinv ⊙ Agg-sum(hp)] @ W2 + b2  (fp32)
  fused_ag_kernel<2><<<gblocks, 512, 0, stream>>>(
      (const uint4*)hp, rowptr, adj, dinv, b2, (const uint4*)Wt2, perm, out, N);
}

// Round 12
// 245.790 us; speedup vs baseline: 4.7982x; 1.0408x over previous
//
#include <hip/hip_runtime.h>
#include <cstdint>
#include <cstddef>

// GCN 2-layer, commuted form:  Agg(z) @ W == Agg(z @ W)  (Agg mixes rows, W mixes cols)
//   s1 = bf16(dinv ⊙ x)
//   h' = dinv ⊙ relu( [dinv ⊙ (s1_i + Σ_nbr s1_r)] @ W1 + b1 )   (bf16, pre-scaled for L2)
//   out =               [dinv ⊙ (h'_i + Σ_nbr h'_r)] @ W2 + b2    (fp32)
//
// R12 = R9 base (246.4us best; bucketing reverted — R11 showed net −9.4us)
// + W-in-k-HALVES LDS staging to hit the 32-wave/CU hardware cap:
//   Wh[128][72] (18.4KB) + Gs[64][136] (17.4KB) = 36.1KB LDS
//   -> 4 blocks/CU x 8 waves = 32 waves/CU (R9: 52.7KB -> 3 blocks, 24 waves).
//   MFMA runs k=0..63 on half1, restages W (k=64..127), runs half2; acc
//   carries across. Cost: +16KB L2-resident W reads/block + 3 barriers.
//   launch_bounds(512,8): VGPR cap 64 (measured usage 40 — safe).

typedef unsigned int u32;
typedef unsigned short u16;
typedef __attribute__((ext_vector_type(8))) short short8;   // 8 bf16 (4 VGPRs)
typedef __attribute__((ext_vector_type(4))) float f32x4;    // MFMA acc / native vec

__device__ __forceinline__ float bf2f(u32 lo16) {
  union { u32 u; float f; } c; c.u = lo16 << 16; return c.f;
}
__device__ __forceinline__ u32 f2bf(float f) {  // round-to-nearest-even
  union { float f; u32 u; } c; c.f = f;
  return (c.u + 0x7fffu + ((c.u >> 16) & 1u)) >> 16;
}

// W1,W2 [k][n] f32 -> Wt [n][k] bf16; zero row N of s1 and hp. 128 blocks.
__global__ __launch_bounds__(256) void wt_kernel(
    const float* __restrict__ W1, const float* __restrict__ W2,
    u16* __restrict__ Wt1, u16* __restrict__ Wt2,
    u16* __restrict__ s1, u16* __restrict__ hp, int N) {
  int gt = blockIdx.x * 256 + threadIdx.x;  // 0..32767
  const float* W = (gt < 16384) ? W1 : W2;
  u16* Wt = (gt < 16384) ? Wt1 : Wt2;
  int idx = gt & 16383;
  Wt[(idx & 127) * 128 + (idx >> 7)] = (u16)f2bf(W[idx]);
  if (gt < 16) {
    ((uint4*)(s1 + (size_t)N * 128))[gt] = make_uint4(0, 0, 0, 0);
    ((uint4*)(hp + (size_t)N * 128))[gt] = make_uint4(0, 0, 0, 0);
  }
}

__global__ __launch_bounds__(256) void count_kernel(
    const int* __restrict__ cols, const int* __restrict__ rows,
    int* __restrict__ cnt, int E, int N) {
  int e = blockIdx.x * 256 + threadIdx.x;
  if (e >= E) return;
  int c = cols[e];
  int r = rows[e];
  if ((unsigned)c >= (unsigned)N || (unsigned)r >= (unsigned)N) return;
  atomicAdd(&cnt[c], 1);
}

// exclusive scan of cnt[N] -> rowptr[N] (chunk-local); emits dinv (fused)
__global__ __launch_bounds__(256) void scan1_kernel(
    const int* __restrict__ cnt, int* __restrict__ rowptr,
    int* __restrict__ bsum, float* __restrict__ dinv, int N) {
  __shared__ int sd[256];
  int t = threadIdx.x;
  int base = blockIdx.x * 1024 + t * 4;
  int c0 = (base + 0 < N) ? cnt[base + 0] : 0;
  int c1 = (base + 1 < N) ? cnt[base + 1] : 0;
  int c2 = (base + 2 < N) ? cnt[base + 2] : 0;
  int c3 = (base + 3 < N) ? cnt[base + 3] : 0;
  if (base + 0 < N) dinv[base + 0] = rsqrtf((float)c0 + 1.0f);
  if (base + 1 < N) dinv[base + 1] = rsqrtf((float)c1 + 1.0f);
  if (base + 2 < N) dinv[base + 2] = rsqrtf((float)c2 + 1.0f);
  if (base + 3 < N) dinv[base + 3] = rsqrtf((float)c3 + 1.0f);
  int s = c0 + c1 + c2 + c3;
  sd[t] = s;
  __syncthreads();
  for (int off = 1; off < 256; off <<= 1) {
    int v = (t >= off) ? sd[t - off] : 0;
    __syncthreads();
    sd[t] += v;
    __syncthreads();
  }
  int excl = sd[t] - s;
  if (base + 0 < N) rowptr[base + 0] = excl;
  if (base + 1 < N) rowptr[base + 1] = excl + c0;
  if (base + 2 < N) rowptr[base + 2] = excl + c0 + c1;
  if (base + 3 < N) rowptr[base + 3] = excl + c0 + c1 + c2;
  if (t == 255) bsum[blockIdx.x] = sd[255];
}

// rowptr += chunk offset (bsum re-scan) AND s1 = bf16(dinv ⊙ x). NB <= 256.
__global__ __launch_bounds__(256) void finalize_kernel(
    const float* __restrict__ x, const float* __restrict__ dinv,
    int* __restrict__ rowptr, const int* __restrict__ bsum,
    u16* __restrict__ s1, int N, int NB) {
  int b = blockIdx.x, t = threadIdx.x;
  if (b < NB) {  // uniform branch per block -> barriers legal
    __shared__ int sd[256];
    int v = (t < NB) ? bsum[t] : 0;
    sd[t] = v;
    __syncthreads();
    for (int off = 1; off < 256; off <<= 1) {
      int u = (t >= off) ? sd[t - off] : 0;
      __syncthreads();
      sd[t] += u;
      __syncthreads();
    }
    int add = (b == 0) ? 0 : sd[b - 1];  // exclusive chunk prefix
    int base = b * 1024 + t * 4;
#pragma unroll
    for (int k = 0; k < 4; k++)
      if (base + k < N) rowptr[base + k] += add;
    if (b == 0 && t == 255) rowptr[N] = sd[255];  // total edges kept
  }
  int total = N * 16;  // 16B chunks per node row
  for (int idx = b * 256 + t; idx < total; idx += gridDim.x * 256) {
    int node = idx >> 4, l = idx & 15;
    float di = dinv[node];
    const float* xp = x + (size_t)node * 128 + l * 8;
    float4 v0 = *(const float4*)xp;
    float4 v1 = *(const float4*)(xp + 4);
    uint4 p;
    p.x = f2bf(di * v0.x) | (f2bf(di * v0.y) << 16);
    p.y = f2bf(di * v0.z) | (f2bf(di * v0.w) << 16);
    p.z = f2bf(di * v1.x) | (f2bf(di * v1.y) << 16);
    p.w = f2bf(di * v1.z) | (f2bf(di * v1.w) << 16);
    ((uint4*)s1)[idx] = p;
  }
}

// cnt doubles as the cursor: atomicSub returns old count, pos = old-1 in [0,deg)
__global__ __launch_bounds__(256) void fill_kernel(
    const int* __restrict__ cols, const int* __restrict__ rows,
    const int* __restrict__ rowptr, int* __restrict__ cnt,
    int* __restrict__ adj, int E, int N) {
  int e = blockIdx.x * 256 + threadIdx.x;
  if (e >= E) return;
  int c = cols[e];
  int r = rows[e];
  if ((unsigned)c >= (unsigned)N || (unsigned)r >= (unsigned)N) return;
  int pos = atomicSub(&cnt[c], 1) - 1;
  if (pos >= 0) adj[rowptr[c] + pos] = r;
}

// ---------------------------------------------------------------------------
// Fused aggregate + GEMM. Block = 512 thr (8 waves), 64 nodes.
// LDS 36.1 KiB -> 4 blocks/CU -> 32 waves/CU (HW cap).
// Phase 1 (gather): quarter-wave per node, 2 passes x 32; rowptr hoisted;
//   fp32 accumulate of src[self] + Σ src[nbr] (zero-row N pads dummies);
//   write dinv*g to Gs (bf16). W k-half 0 staged concurrently.
// Phase 2 (MFMA, two k-halves): wave = (mt, nhalf): 16 rows x 64 cols,
//   4 nt x 2 k-steps per half of 16x16x32 bf16, A from Gs, B from Wh;
//   restage Wh between halves (acc carries). Layouts (m89/m118-verified):
//   A: lane holds A[m=lane&15][k=quad*8+j];  B: B[k=quad*8+j][n=lane&15]
//   C/D: col=lane&15, row=quad*4+reg
// Epilogue L1: hp = bf16(dinv*relu(acc+b1)) via Gs reuse, coalesced uint4.
// Epilogue L2: out = fp32(acc+b2) via fp32 overlay [64][132] of smem,
//   nontemporal f32x4 stores.
// ---------------------------------------------------------------------------
template <int LAYER>
__global__ __launch_bounds__(512, 8) void fused_ag_kernel(
    const uint4* __restrict__ src, const int* __restrict__ rowptr,
    const int* __restrict__ adj, const float* __restrict__ dinv,
    const float* __restrict__ bias, const uint4* __restrict__ Wt,
    void* __restrict__ out, int N) {
  __shared__ __align__(16) u16 smem[128 * 72 + 64 * 136];  // Wh | Gs = 35840 B
  __shared__ float dv_s[64];
  u16 (*Wh)[72] = (u16(*)[72])smem;                  // 18432 B (W k-half, [n][kk])
  u16 (*Gs)[136] = (u16(*)[136])(smem + 128 * 72);   // 17408 B (gathered rows)
  const int tid = threadIdx.x;
  const int row0 = blockIdx.x * 64;

  // stage W k-half 0 (1024 x 16B, 512 thr x 2); Wt row n = 16 uint4
#pragma unroll
  for (int i = 0; i < 2; i++) {
    int linear = tid + i * 512;           // 0..1023
    int n = linear >> 3, kq = linear & 7; // 8 uint4 per row-half
    *(uint4*)&Wh[n][kq * 8] = Wt[n * 16 + kq];
  }

  // ---- gather phase: 2 passes x 32 nodes (quarter-wave per node)
  const int qw = tid >> 4;   // 0..31
  const int l = tid & 15;
  int begs[2], ends[2];
#pragma unroll
  for (int p = 0; p < 2; ++p) {
    int node = row0 + p * 32 + qw;
    begs[p] = 0; ends[p] = 0;
    if (node < N) { begs[p] = rowptr[node]; ends[p] = rowptr[node + 1]; }
  }
#pragma unroll
  for (int pass = 0; pass < 2; ++pass) {
    int lrow = pass * 32 + qw;
    int node = row0 + lrow;
    float a[8] = {0.f, 0.f, 0.f, 0.f, 0.f, 0.f, 0.f, 0.f};
    float di = 0.f;
    if (node < N) {
      di = dinv[node];
      uint4 sv = src[(size_t)node * 16 + l];
      a[0] = bf2f(sv.x & 0xffff); a[1] = bf2f(sv.x >> 16);
      a[2] = bf2f(sv.y & 0xffff); a[3] = bf2f(sv.y >> 16);
      a[4] = bf2f(sv.z & 0xffff); a[5] = bf2f(sv.z >> 16);
      a[6] = bf2f(sv.w & 0xffff); a[7] = bf2f(sv.w >> 16);
      int beg = begs[pass], end = ends[pass];
      for (int j = beg; j < end; j += 8) {
        int sidx[8];
#pragma unroll
        for (int k = 0; k < 8; k++) {
          int jj = j + k;
          sidx[k] = (jj < end) ? adj[jj] : N;  // N = zero row
        }
        uint4 v[8];
#pragma unroll
        for (int k = 0; k < 8; k++) v[k] = src[(size_t)sidx[k] * 16 + l];
#pragma unroll
        for (int k = 0; k < 8; k++) {
          a[0] += bf2f(v[k].x & 0xffff); a[1] += bf2f(v[k].x >> 16);
          a[2] += bf2f(v[k].y & 0xffff); a[3] += bf2f(v[k].y >> 16);
          a[4] += bf2f(v[k].z & 0xffff); a[5] += bf2f(v[k].z >> 16);
          a[6] += bf2f(v[k].w & 0xffff); a[7] += bf2f(v[k].w >> 16);
        }
      }
    }
    uint4 p;
    p.x = f2bf(di * a[0]) | (f2bf(di * a[1]) << 16);
    p.y = f2bf(di * a[2]) | (f2bf(di * a[3]) << 16);
    p.z = f2bf(di * a[4]) | (f2bf(di * a[5]) << 16);
    p.w = f2bf(di * a[6]) | (f2bf(di * a[7]) << 16);
    *(uint4*)&Gs[lrow][l * 8] = p;
    if (l == 0) dv_s[lrow] = di;
  }

  // ---- MFMA phase (two k-halves): wave (mt, nhalf) owns 16 rows x 64 cols
  const int wave = tid >> 6, lane = tid & 63;
  const int lm = lane & 15, quad = lane >> 4;
  const int m0 = (wave >> 1) * 16;
  const int nh = wave & 1;

  float bv[4];
#pragma unroll
  for (int nt = 0; nt < 4; nt++) bv[nt] = bias[(nh * 4 + nt) * 16 + lm];

  f32x4 acc[4];
#pragma unroll
  for (int nt = 0; nt < 4; nt++) acc[nt] = (f32x4){0.f, 0.f, 0.f, 0.f};

  __syncthreads();  // Gs + Wh(half 0) ready
#pragma unroll
  for (int k0 = 0; k0 < 64; k0 += 32) {
    short8 afrag = *(const short8*)&Gs[m0 + lm][k0 + quad * 8];
#pragma unroll
    for (int nt = 0; nt < 4; nt++) {
      short8 bfrag = *(const short8*)&Wh[(nh * 4 + nt) * 16 + lm][k0 + quad * 8];
      acc[nt] = __builtin_amdgcn_mfma_f32_16x16x32_bf16(afrag, bfrag, acc[nt], 0, 0, 0);
    }
  }
  __syncthreads();  // all waves done reading Wh half 0
#pragma unroll
  for (int i = 0; i < 2; i++) {  // stage W k-half 1
    int linear = tid + i * 512;
    int n = linear >> 3, kq = linear & 7;
    *(uint4*)&Wh[n][kq * 8] = Wt[n * 16 + 8 + kq];
  }
  __syncthreads();  // Wh half 1 ready
#pragma unroll
  for (int k0 = 0; k0 < 64; k0 += 32) {
    short8 afrag = *(const short8*)&Gs[m0 + lm][64 + k0 + quad * 8];
#pragma unroll
    for (int nt = 0; nt < 4; nt++) {
      short8 bfrag = *(const short8*)&Wh[(nh * 4 + nt) * 16 + lm][k0 + quad * 8];
      acc[nt] = __builtin_amdgcn_mfma_f32_16x16x32_bf16(afrag, bfrag, acc[nt], 0, 0, 0);
    }
  }

  __syncthreads();  // Wh/Gs dead; reuse as epilogue staging
  if (LAYER == 1) {
    int rbase = m0 + quad * 4;
#pragma unroll
    for (int r = 0; r < 4; r++) {
      int lrow = rbase + r;
      float dv = dv_s[lrow];
#pragma unroll
      for (int nt = 0; nt < 4; nt++) {
        float v = fmaxf(acc[nt][r] + bv[nt], 0.f);
        Gs[lrow][(nh * 4 + nt) * 16 + lm] = (u16)f2bf(v * dv);
      }
    }
    __syncthreads();
    u16* C = (u16*)out;
#pragma unroll
    for (int i = 0; i < 2; i++) {
      int linear = tid + i * 512;  // 0..1023 = 64 rows x 16 uint4-chunks
      int row = linear >> 4, c8 = linear & 15;
      int grow = row0 + row;
      if (grow < N)
        *(uint4*)(C + (size_t)grow * 128 + c8 * 8) = *(const uint4*)&Gs[row][c8 * 8];
    }
  } else {
    float (*Fs)[132] = (float(*)[132])smem;  // 64*132*4 = 33792 B <= 35840
    int rbase = m0 + quad * 4;
#pragma unroll
    for (int r = 0; r < 4; r++) {
      int lrow = rbase + r;
#pragma unroll
      for (int nt = 0; nt < 4; nt++)
        Fs[lrow][(nh * 4 + nt) * 16 + lm] = acc[nt][r] + bv[nt];
    }
    __syncthreads();
    float* C = (float*)out;
#pragma unroll
    for (int i = 0; i < 4; i++) {
      int linear = tid + i * 512;  // 0..2047 = 64 rows x 32 f32x4-chunks
      int row = linear >> 5, c4 = linear & 31;
      int grow = row0 + row;
      if (grow < N) {
        f32x4 v = *(const f32x4*)&Fs[row][c4 * 4];
        __builtin_nontemporal_store(v, (f32x4*)(C + (size_t)grow * 128 + c4 * 4));
      }
    }
  }
}

extern "C" void kernel_launch(void* const* d_in, const int* in_sizes, int n_in,
                              void* d_out, int out_size, void* d_ws, size_t ws_size,
                              hipStream_t stream) {
  const float* x  = (const float*)d_in[0];
  const int*   ei = (const int*)d_in[1];
  const float* W1 = (const float*)d_in[2];
  const float* b1 = (const float*)d_in[3];
  const float* W2 = (const float*)d_in[4];
  const float* b2 = (const float*)d_in[5];
  float* out = (float*)d_out;

  const int F = 128;
  const int N = in_sizes[0] / F;
  const int E = in_sizes[1] / 2;
  const int* rows = ei;       // edge_index[0] = source
  const int* cols = ei + E;   // edge_index[1] = destination

  // workspace layout (~55 MB)
  u16*   Wt1    = (u16*)d_ws;                          // 128*128 bf16 (W1^T)
  u16*   Wt2    = Wt1 + 128 * 128;                     // 128*128 bf16 (W2^T)
  u16*   s1     = Wt2 + 128 * 128;                     // (N+1)*128 bf16 (dinv⊙x + zero row)
  u16*   hp     = s1 + (size_t)(N + 1) * F;            // (N+1)*128 bf16 (dinv⊙h + zero row)
  float* dinv   = (float*)(hp + (size_t)(N + 1) * F);  // N f32
  int*   cnt    = (int*)(dinv + N);                    // N i32 (count, then cursor)
  int*   rowptr = cnt + N;                             // N+1 i32
  int*   adj    = rowptr + (N + 1);                    // E i32
  int*   bsum   = adj + E;                             // 256 i32

  const int NB = (N + 1023) / 1024;  // <= 256 (N <= 262144)
  int eblocks = (E + 255) / 256;
  int fblocks = (NB > 784) ? NB : 784;

  hipMemsetAsync(cnt, 0, (size_t)N * sizeof(int), stream);
  wt_kernel<<<128, 256, 0, stream>>>(W1, W2, Wt1, Wt2, s1, hp, N);
  count_kernel<<<eblocks, 256, 0, stream>>>(cols, rows, cnt, E, N);
  scan1_kernel<<<NB, 256, 0, stream>>>(cnt, rowptr, bsum, dinv, N);
  finalize_kernel<<<fblocks, 256, 0, stream>>>(x, dinv, rowptr, bsum, s1, N, NB);
  fill_kernel<<<eblocks, 256, 0, stream>>>(cols, rows, rowptr, cnt, adj, E, N);

  int gblocks = (N + 63) / 64;
  // layer 1: hp = dinv ⊙ relu([dinv ⊙ Agg-sum(s1)] @ W1 + b1)  (bf16)
  fused_ag_kernel<1><<<gblocks, 512, 0, stream>>>(
      (const uint4*)s1, rowptr, adj, dinv, b1, (const uint4*)Wt1, hp, N);
  // layer 2: out = [dinv ⊙ Agg-sum(hp)] @ W2 + b2  (fp32)
  fused_ag_kernel<2><<<gblocks, 512, 0, stream>>>(
      (const uint4*)hp, rowptr, adj, dinv, b2, (const uint4*)Wt2, out, N);
}